// Round 14
// baseline (982.139 us; speedup 1.0000x reference)
//
#include <hip/hip_runtime.h>

#define BATCH 256
#define TLEN  512
#define DIN   64
#define HID   128
#define NOUT  40
#define SC    16
#define NCH   (TLEN / SC)    // 32 chunks per layer

typedef _Float16 f16x8 __attribute__((ext_vector_type(8)));
typedef float    f32x4 __attribute__((ext_vector_type(4)));

#define MFMA16(a, b, c) __builtin_amdgcn_mfma_f32_16x16x32_f16((a), (b), (c), 0, 0, 0)
#define SCHED_FENCE() __builtin_amdgcn_sched_barrier(0)

// LDS-visibility barrier only: no vmcnt drain.
#define BARRIER() do {                                      \
    asm volatile("s_waitcnt lgkmcnt(0)" ::: "memory");      \
    __builtin_amdgcn_s_barrier();                           \
} while (0)

static __device__ __forceinline__ f16x8 pack8(float4 a, float4 b) {
    f16x8 v;
    v[0] = (_Float16)a.x; v[1] = (_Float16)a.y; v[2] = (_Float16)a.z; v[3] = (_Float16)a.w;
    v[4] = (_Float16)b.x; v[5] = (_Float16)b.y; v[6] = (_Float16)b.z; v[7] = (_Float16)b.w;
    return v;
}
static __device__ __forceinline__ float sig_(float x) {
    return __builtin_amdgcn_rcpf(1.0f + __expf(-x));
}
static __device__ __forceinline__ float tanh_(float x) {
    return fmaf(-2.0f, __builtin_amdgcn_rcpf(__expf(2.0f * x) + 1.0f), 1.0f);
}
static __device__ __forceinline__ f32x4 splat4(float v) { return (f32x4){v, v, v, v}; }

// Weight fragment loader; uses kernel-local `kg`. k = kt*32 + kg*8 + j.
#define LD8(base, g, K, kt) pack8(*(const float4*)((base) + (size_t)(g) * (K) + (kt) * 32 + kg * 8), \
                                  *(const float4*)((base) + (size_t)(g) * (K) + (kt) * 32 + kg * 8 + 4))

// ====== Producer-consumer 2-layer LSTM ======
// 512 blocks x 256 thr (4 waves). Even blocks: layer 0 for batch b=blockIdx>>1;
// odd blocks: layer 1. Wave w owns hid [w*32, w*32+32) (tiles A and B).
// l0 writes y0 chunks to a global slab + release-flag; l1 acquire-spins then
// consumes. Independent per-block barriers -> one block's ACT/barrier hides
// under the other's MFMAs on the shared SIMD. l0 never waits (full slab) ->
// deadlock-free even without co-residency (degrades to sequential).
__global__ void __attribute__((amdgpu_flat_work_group_size(256, 256), amdgpu_waves_per_eu(2, 2)))
lstm_pipe(const float* __restrict__ x,
          const float* __restrict__ Wih0, const float* __restrict__ Whh0,
          const float* __restrict__ bih0, const float* __restrict__ bhh0,
          const float* __restrict__ Wih1, const float* __restrict__ Whh1,
          const float* __restrict__ bih1, const float* __restrict__ bhh1,
          const float* __restrict__ Wfc,  const float* __restrict__ bfc,
          _Float16* __restrict__ y0g, int* __restrict__ prod,
          float* __restrict__ out)
{
    const int role = blockIdx.x & 1;          // 0 = layer0, 1 = layer1
    const int b    = blockIdx.x >> 1;
    const int tid  = threadIdx.x;
    const int lane = tid & 63, wave = tid >> 6;
    const int col  = lane & 15, kg = lane >> 4;
    const int hidA = wave * 32 + col;
    const int hidB = hidA + 16;

    __shared__ __align__(16) float    acc_lds[SC * HID * 4];   // 32 KB input-proj
    __shared__ __align__(16) _Float16 h_lds[2][HID];

    const float* Whh = role ? Whh1 : Whh0;
    const float* Wih = role ? Wih1 : Wih0;
    const float* bi  = role ? bih1 : bih0;
    const float* bh  = role ? bhh1 : bhh0;

    // ---- recurrent weights for this block's layer: 32 frags -> 128 AGPR ----
    f16x8 WA00 = LD8(Whh, 0 * HID + hidA, HID, 0), WA01 = LD8(Whh, 0 * HID + hidA, HID, 1);
    f16x8 WA02 = LD8(Whh, 0 * HID + hidA, HID, 2), WA03 = LD8(Whh, 0 * HID + hidA, HID, 3);
    f16x8 WA10 = LD8(Whh, 1 * HID + hidA, HID, 0), WA11 = LD8(Whh, 1 * HID + hidA, HID, 1);
    f16x8 WA12 = LD8(Whh, 1 * HID + hidA, HID, 2), WA13 = LD8(Whh, 1 * HID + hidA, HID, 3);
    f16x8 WA20 = LD8(Whh, 2 * HID + hidA, HID, 0), WA21 = LD8(Whh, 2 * HID + hidA, HID, 1);
    f16x8 WA22 = LD8(Whh, 2 * HID + hidA, HID, 2), WA23 = LD8(Whh, 2 * HID + hidA, HID, 3);
    f16x8 WA30 = LD8(Whh, 3 * HID + hidA, HID, 0), WA31 = LD8(Whh, 3 * HID + hidA, HID, 1);
    f16x8 WA32 = LD8(Whh, 3 * HID + hidA, HID, 2), WA33 = LD8(Whh, 3 * HID + hidA, HID, 3);
    f16x8 WB00 = LD8(Whh, 0 * HID + hidB, HID, 0), WB01 = LD8(Whh, 0 * HID + hidB, HID, 1);
    f16x8 WB02 = LD8(Whh, 0 * HID + hidB, HID, 2), WB03 = LD8(Whh, 0 * HID + hidB, HID, 3);
    f16x8 WB10 = LD8(Whh, 1 * HID + hidB, HID, 0), WB11 = LD8(Whh, 1 * HID + hidB, HID, 1);
    f16x8 WB12 = LD8(Whh, 1 * HID + hidB, HID, 2), WB13 = LD8(Whh, 1 * HID + hidB, HID, 3);
    f16x8 WB20 = LD8(Whh, 2 * HID + hidB, HID, 0), WB21 = LD8(Whh, 2 * HID + hidB, HID, 1);
    f16x8 WB22 = LD8(Whh, 2 * HID + hidB, HID, 2), WB23 = LD8(Whh, 2 * HID + hidB, HID, 3);
    f16x8 WB30 = LD8(Whh, 3 * HID + hidB, HID, 0), WB31 = LD8(Whh, 3 * HID + hidB, HID, 1);
    f16x8 WB32 = LD8(Whh, 3 * HID + hidB, HID, 2), WB33 = LD8(Whh, 3 * HID + hidB, HID, 3);
    asm("" : "+a"(WA00), "+a"(WA01), "+a"(WA02), "+a"(WA03),
             "+a"(WA10), "+a"(WA11), "+a"(WA12), "+a"(WA13));
    asm("" : "+a"(WA20), "+a"(WA21), "+a"(WA22), "+a"(WA23),
             "+a"(WA30), "+a"(WA31), "+a"(WA32), "+a"(WA33));
    asm("" : "+a"(WB00), "+a"(WB01), "+a"(WB02), "+a"(WB03),
             "+a"(WB10), "+a"(WB11), "+a"(WB12), "+a"(WB13));
    asm("" : "+a"(WB20), "+a"(WB21), "+a"(WB22), "+a"(WB23),
             "+a"(WB30), "+a"(WB31), "+a"(WB32), "+a"(WB33));

    float ccA = 0.f, ccB = 0.f, hvA = 0.f, hvB = 0.f;
    if (tid < HID) h_lds[0][tid] = (_Float16)0.f;
    __syncthreads();

// ---- XPROJ (l0): A held (16 regs), W transient per single-gate pass ----
#define XP_PASS(N, A0, A1) do {                                                  \
    f16x8 Wt0 = LD8(Wih, (N) * HID + hidA, DIN, 0);                              \
    f16x8 Wt1 = LD8(Wih, (N) * HID + hidA, DIN, 1);                              \
    f16x8 Wu0 = LD8(Wih, (N) * HID + hidB, DIN, 0);                              \
    f16x8 Wu1 = LD8(Wih, (N) * HID + hidB, DIN, 1);                              \
    f32x4 gA = splat4(bi[(N) * HID + hidA] + bh[(N) * HID + hidA]);              \
    f32x4 gB = splat4(bi[(N) * HID + hidB] + bh[(N) * HID + hidB]);              \
    gA = MFMA16(A0, Wt0, gA); gA = MFMA16(A1, Wt1, gA);                          \
    gB = MFMA16(A0, Wu0, gB); gB = MFMA16(A1, Wu1, gB);                          \
    _Pragma("unroll") for (int r = 0; r < 4; ++r) {                              \
        acc_lds[((kg * 4 + r) * HID + hidA) * 4 + (N)] = gA[r];                  \
        acc_lds[((kg * 4 + r) * HID + hidB) * 4 + (N)] = gB[r];                  \
    }                                                                            \
} while (0)

// ---- YPROJ (l1): A from global y0 slab (rows = 16 timesteps = col) ----
#define YP_PASS(N, A0, A1, A2, A3) do {                                          \
    f16x8 Wt0 = LD8(Wih, (N) * HID + hidA, HID, 0);                              \
    f16x8 Wt1 = LD8(Wih, (N) * HID + hidA, HID, 1);                              \
    f16x8 Wt2 = LD8(Wih, (N) * HID + hidA, HID, 2);                              \
    f16x8 Wt3 = LD8(Wih, (N) * HID + hidA, HID, 3);                              \
    f16x8 Wu0 = LD8(Wih, (N) * HID + hidB, HID, 0);                              \
    f16x8 Wu1 = LD8(Wih, (N) * HID + hidB, HID, 1);                              \
    f16x8 Wu2 = LD8(Wih, (N) * HID + hidB, HID, 2);                              \
    f16x8 Wu3 = LD8(Wih, (N) * HID + hidB, HID, 3);                              \
    f32x4 gA = splat4(bi[(N) * HID + hidA] + bh[(N) * HID + hidA]);              \
    f32x4 gB = splat4(bi[(N) * HID + hidB] + bh[(N) * HID + hidB]);              \
    gA = MFMA16(A0, Wt0, gA); gA = MFMA16(A1, Wt1, gA);                          \
    gA = MFMA16(A2, Wt2, gA); gA = MFMA16(A3, Wt3, gA);                          \
    gB = MFMA16(A0, Wu0, gB); gB = MFMA16(A1, Wu1, gB);                          \
    gB = MFMA16(A2, Wu2, gB); gB = MFMA16(A3, Wu3, gB);                          \
    _Pragma("unroll") for (int r = 0; r < 4; ++r) {                              \
        acc_lds[((kg * 4 + r) * HID + hidA) * 4 + (N)] = gA[r];                  \
        acc_lds[((kg * 4 + r) * HID + hidB) * 4 + (N)] = gB[r];                  \
    }                                                                            \
} while (0)

// ---- steady step: 32 MFMA (8 chains of 4) + 2-cell ACT, one barrier ----
#define STEP_CORE(S, P, C) do {                                                  \
    f32x4 xiA = *(const f32x4*)&acc_lds[((S) * HID + hidA) * 4];                 \
    f32x4 xiB = *(const f32x4*)&acc_lds[((S) * HID + hidB) * 4];                 \
    const _Float16* hb = &h_lds[P][0];                                           \
    f16x8 h0 = *(const f16x8*)(hb + kg * 8);                                     \
    f16x8 h1 = *(const f16x8*)(hb + 32 + kg * 8);                                \
    f16x8 h2 = *(const f16x8*)(hb + 64 + kg * 8);                                \
    f16x8 h3 = *(const f16x8*)(hb + 96 + kg * 8);                                \
    f32x4 aA0 = MFMA16(h0, WA00, xiA);                                           \
    f32x4 aA1 = MFMA16(h0, WA10, splat4(xiA[1]));                                \
    f32x4 aA2 = MFMA16(h0, WA20, splat4(xiA[2]));                                \
    f32x4 aA3 = MFMA16(h0, WA30, splat4(xiA[3]));                                \
    f32x4 aB0 = MFMA16(h0, WB00, xiB);                                           \
    f32x4 aB1 = MFMA16(h0, WB10, splat4(xiB[1]));                                \
    f32x4 aB2 = MFMA16(h0, WB20, splat4(xiB[2]));                                \
    f32x4 aB3 = MFMA16(h0, WB30, splat4(xiB[3]));                                \
    aA0 = MFMA16(h1, WA01, aA0); aA1 = MFMA16(h1, WA11, aA1);                    \
    aA2 = MFMA16(h1, WA21, aA2); aA3 = MFMA16(h1, WA31, aA3);                    \
    aB0 = MFMA16(h1, WB01, aB0); aB1 = MFMA16(h1, WB11, aB1);                    \
    aB2 = MFMA16(h1, WB21, aB2); aB3 = MFMA16(h1, WB31, aB3);                    \
    aA0 = MFMA16(h2, WA02, aA0); aA1 = MFMA16(h2, WA12, aA1);                    \
    aA2 = MFMA16(h2, WA22, aA2); aA3 = MFMA16(h2, WA32, aA3);                    \
    aB0 = MFMA16(h2, WB02, aB0); aB1 = MFMA16(h2, WB12, aB1);                    \
    aB2 = MFMA16(h2, WB22, aB2); aB3 = MFMA16(h2, WB32, aB3);                    \
    aA0 = MFMA16(h3, WA03, aA0); aA1 = MFMA16(h3, WA13, aA1);                    \
    aA2 = MFMA16(h3, WA23, aA2); aA3 = MFMA16(h3, WA33, aA3);                    \
    aB0 = MFMA16(h3, WB03, aB0); aB1 = MFMA16(h3, WB13, aB1);                    \
    aB2 = MFMA16(h3, WB23, aB2); aB3 = MFMA16(h3, WB33, aB3);                    \
    float ivA = sig_(aA0[0]), fvA = sig_(aA1[0]);                                \
    float gvA = tanh_(aA2[0]), ovA = sig_(aA3[0]);                               \
    ccA = fmaf(fvA, ccA, ivA * gvA);                                             \
    hvA = ovA * tanh_(ccA);                                                      \
    float ivB = sig_(aB0[0]), fvB = sig_(aB1[0]);                                \
    float gvB = tanh_(aB2[0]), ovB = sig_(aB3[0]);                               \
    ccB = fmaf(fvB, ccB, ivB * gvB);                                             \
    hvB = ovB * tanh_(ccB);                                                      \
    if (kg == 0) {                                                               \
        _Float16 hA = (_Float16)hvA, hB = (_Float16)hvB;                         \
        h_lds[(P) ^ 1][hidA] = hA;                                               \
        h_lds[(P) ^ 1][hidB] = hB;                                               \
        if (role == 0) {                                                         \
            _Float16* yp = y0g + ((size_t)b * TLEN + (size_t)(C) * SC + (S)) * HID; \
            yp[hidA] = hA; yp[hidB] = hB;                                        \
        }                                                                        \
    }                                                                            \
    BARRIER();                                                                   \
} while (0)

    for (int c = 0; c < NCH; ++c) {
        if (role == 0) {
            const float* pa = x + ((size_t)b * TLEN + (size_t)c * SC + col) * DIN + kg * 8;
            f16x8 A0 = pack8(*(const float4*)pa,        *(const float4*)(pa + 4));
            f16x8 A1 = pack8(*(const float4*)(pa + 32), *(const float4*)(pa + 36));
            XP_PASS(0, A0, A1); SCHED_FENCE();
            XP_PASS(1, A0, A1); SCHED_FENCE();
            XP_PASS(2, A0, A1); SCHED_FENCE();
            XP_PASS(3, A0, A1);
        } else {
            if (tid == 0) {
                while (__hip_atomic_load(&prod[b], __ATOMIC_ACQUIRE,
                                         __HIP_MEMORY_SCOPE_AGENT) <= c)
                    __builtin_amdgcn_s_sleep(4);
            }
            __syncthreads();
            const _Float16* pa = y0g + ((size_t)b * TLEN + (size_t)c * SC + col) * HID + kg * 8;
            f16x8 A0 = *(const f16x8*)(pa);
            f16x8 A1 = *(const f16x8*)(pa + 32);
            f16x8 A2 = *(const f16x8*)(pa + 64);
            f16x8 A3 = *(const f16x8*)(pa + 96);
            YP_PASS(0, A0, A1, A2, A3); SCHED_FENCE();
            YP_PASS(1, A0, A1, A2, A3); SCHED_FENCE();
            YP_PASS(2, A0, A1, A2, A3); SCHED_FENCE();
            YP_PASS(3, A0, A1, A2, A3);
        }
        BARRIER();
        for (int s = 0; s < SC; s += 2) {
            STEP_CORE(s,     0, c);
            STEP_CORE(s + 1, 1, c);
        }
        if (role == 0) {
            __syncthreads();   // vmcnt drain: all y0 stores complete
            if (tid == 0)
                __hip_atomic_store(&prod[b], c + 1, __ATOMIC_RELEASE,
                                   __HIP_MEMORY_SCOPE_AGENT);
        }
    }

    // ---- fused FC on l1 blocks: out[b][o] = h1 · Wfc[o] + bfc[o] ----
    if (role == 1) {
        float* h1f = acc_lds;
        if (kg == 0) { h1f[hidA] = hvA; h1f[hidB] = hvB; }
        __syncthreads();
        if (tid < NOUT) {
            const float4* w   = (const float4*)(Wfc + (size_t)tid * HID);
            const float4* hv4 = (const float4*)h1f;
            float acc = bfc[tid];
            #pragma unroll
            for (int q = 0; q < HID / 4; ++q) {
                float4 wv = w[q]; float4 h4 = hv4[q];
                acc = fmaf(wv.x, h4.x, fmaf(wv.y, h4.y, fmaf(wv.z, h4.z, fmaf(wv.w, h4.w, acc))));
            }
            out[(size_t)b * NOUT + tid] = acc;
        }
    }
}

extern "C" void kernel_launch(void* const* d_in, const int* in_sizes, int n_in,
                              void* d_out, int out_size, void* d_ws, size_t ws_size,
                              hipStream_t stream) {
    const float* x    = (const float*)d_in[0];
    const float* Wih0 = (const float*)d_in[1];
    const float* Whh0 = (const float*)d_in[2];
    const float* bih0 = (const float*)d_in[3];
    const float* bhh0 = (const float*)d_in[4];
    const float* Wih1 = (const float*)d_in[5];
    const float* Whh1 = (const float*)d_in[6];
    const float* bih1 = (const float*)d_in[7];
    const float* bhh1 = (const float*)d_in[8];
    const float* Wfc  = (const float*)d_in[9];
    const float* bfc  = (const float*)d_in[10];
    float* out = (float*)d_out;

    // ws: y0 slab [B][T][H] f16 (33.5 MB) | prod flags [B] int
    _Float16* y0g = (_Float16*)d_ws;
    int* prod = (int*)((char*)d_ws + (size_t)BATCH * TLEN * HID * sizeof(_Float16));

    hipMemsetAsync(prod, 0, BATCH * sizeof(int), stream);
    lstm_pipe<<<2 * BATCH, 256, 0, stream>>>(x, Wih0, Whh0, bih0, bhh0,
                                             Wih1, Whh1, bih1, bhh1,
                                             Wfc, bfc, y0g, prod, out);
}

// Round 15
// 611.482 us; speedup vs baseline: 1.6062x; 1.6062x over previous
//
#include <hip/hip_runtime.h>

#define BATCH 256
#define TLEN  512
#define DIN   64
#define HID   128
#define NOUT  40
#define SC    16   // sub-chunk: input projections precomputed 16 steps at a time

typedef _Float16 f16x8 __attribute__((ext_vector_type(8)));
typedef float    f32x4 __attribute__((ext_vector_type(4)));

#define MFMA16(a, b, c) __builtin_amdgcn_mfma_f32_16x16x32_f16((a), (b), (c), 0, 0, 0)

// In-place MFMA accumulate, B consumed DIRECTLY from AGPR (no accvgpr_read).
static __device__ __forceinline__ void mfma_acc_a(f32x4& d, f16x8 a, f16x8 b) {
    asm volatile("v_mfma_f32_16x16x32_f16 %0, %1, %2, %0"
                 : "+v"(d) : "v"(a), "a"(b));
}
// Hazard guard: VALU may not read an asm-MFMA result until the pipe drains.
// In/out deps order this between the MFMA cluster and ACT's first read.
static __device__ __forceinline__ void mfma_guard(f32x4& d0, f32x4& d1,
                                                  f32x4& d2, f32x4& d3) {
    asm volatile("s_nop 7\n\ts_nop 7\n\ts_nop 7"
                 : "+v"(d0), "+v"(d1), "+v"(d2), "+v"(d3));
}

// LDS-visibility barrier only: no vmcnt drain.
#define BARRIER() do {                                      \
    asm volatile("s_waitcnt lgkmcnt(0)" ::: "memory");      \
    __builtin_amdgcn_s_barrier();                           \
} while (0)

static __device__ __forceinline__ f16x8 pack8(float4 a, float4 b) {
    f16x8 v;
    v[0] = (_Float16)a.x; v[1] = (_Float16)a.y; v[2] = (_Float16)a.z; v[3] = (_Float16)a.w;
    v[4] = (_Float16)b.x; v[5] = (_Float16)b.y; v[6] = (_Float16)b.z; v[7] = (_Float16)b.w;
    return v;
}
static __device__ __forceinline__ float sig_(float x) {
    return __builtin_amdgcn_rcpf(1.0f + __expf(-x));
}
static __device__ __forceinline__ float tanh_(float x) {
    return fmaf(-2.0f, __builtin_amdgcn_rcpf(__expf(2.0f * x) + 1.0f), 1.0f);
}
static __device__ __forceinline__ f32x4 splat4(float v) { return (f32x4){v, v, v, v}; }

// Weight fragment loader; uses kernel-local `kg`. k = kt*32 + kg*8 + j.
#define LD8(base, g, K, kt) pack8(*(const float4*)((base) + (size_t)(g) * (K) + (kt) * 32 + kg * 8), \
                                  *(const float4*)((base) + (size_t)(g) * (K) + (kt) * 32 + kg * 8 + 4))

// Steady-state recurrent step: 16 h-MFMAs (asm, AGPR-direct), C-init from
// precomputed input acc. Uses kernel-locals: xacc, h_lds, hid, kg, cc, hv.
#define H_STEP_CORE(SL, P)                                                      \
    f32x4 xi = *(const f32x4*)&xacc[((SL) * HID + hid) * 4];                    \
    const _Float16* hb = &h_lds[P][0];                                          \
    f16x8 h0 = *(const f16x8*)(hb + kg * 8);                                    \
    f16x8 h1 = *(const f16x8*)(hb + 32 + kg * 8);                               \
    f16x8 h2 = *(const f16x8*)(hb + 64 + kg * 8);                               \
    f16x8 h3 = *(const f16x8*)(hb + 96 + kg * 8);                               \
    f32x4 a0 = xi;                                                              \
    f32x4 a1 = splat4(xi[1]);                                                   \
    f32x4 a2 = splat4(xi[2]);                                                   \
    f32x4 a3 = splat4(xi[3]);                                                   \
    mfma_acc_a(a0, h0, Wh00); mfma_acc_a(a1, h0, Wh10);                         \
    mfma_acc_a(a2, h0, Wh20); mfma_acc_a(a3, h0, Wh30);                         \
    mfma_acc_a(a0, h1, Wh01); mfma_acc_a(a1, h1, Wh11);                         \
    mfma_acc_a(a2, h1, Wh21); mfma_acc_a(a3, h1, Wh31);                         \
    mfma_acc_a(a0, h2, Wh02); mfma_acc_a(a1, h2, Wh12);                         \
    mfma_acc_a(a2, h2, Wh22); mfma_acc_a(a3, h2, Wh32);                         \
    mfma_acc_a(a0, h3, Wh03); mfma_acc_a(a1, h3, Wh13);                         \
    mfma_acc_a(a2, h3, Wh23); mfma_acc_a(a3, h3, Wh33);                         \
    mfma_guard(a0, a1, a2, a3);                                                 \
    float iv = sig_(a0[0]), fv = sig_(a1[0]);                                   \
    float gv = tanh_(a2[0]), ov = sig_(a3[0]);                                  \
    cc = fmaf(fv, cc, iv * gv);                                                 \
    hv = ov * tanh_(cc);

// ===================== Layer 0 =====================
// 256 blocks (one batch) x 512 thr (8 waves). Wave w owns hid [w*16,w*16+16).
// Per SC steps: GEMM phase computes xacc[t][hid][i,f,g,o] = bias + x_t·Wx with
// M=16 (timesteps as A-rows). Steady step: 16 h-MFMAs only, C-init from xacc.
__global__ void __attribute__((amdgpu_flat_work_group_size(512, 512), amdgpu_waves_per_eu(2, 2)))
lstm_l0(const float* __restrict__ x,
        const float* __restrict__ Wih, const float* __restrict__ Whh,
        const float* __restrict__ bih, const float* __restrict__ bhh,
        float* __restrict__ hstate, float* __restrict__ cstate,
        _Float16* __restrict__ y0, int t0, int t1)
{
    const int b    = blockIdx.x;
    const int tid  = threadIdx.x;
    const int lane = tid & 63;
    const int wave = tid >> 6;
    const int col  = lane & 15, kg = lane >> 4;
    const int hid  = wave * 16 + col;

    __shared__ __align__(16) float    xacc[SC * HID * 4];   // 32 KB: [(tl*128+hid)*4 + n]
    __shared__ __align__(16) _Float16 h_lds[2][HID];

    // ---- weight fragments (AGPR-pinned; consumed in place by asm MFMA) ----
    f16x8 Wx00 = LD8(Wih, 0 * HID + hid, DIN, 0), Wx01 = LD8(Wih, 0 * HID + hid, DIN, 1);
    f16x8 Wx10 = LD8(Wih, 1 * HID + hid, DIN, 0), Wx11 = LD8(Wih, 1 * HID + hid, DIN, 1);
    f16x8 Wx20 = LD8(Wih, 2 * HID + hid, DIN, 0), Wx21 = LD8(Wih, 2 * HID + hid, DIN, 1);
    f16x8 Wx30 = LD8(Wih, 3 * HID + hid, DIN, 0), Wx31 = LD8(Wih, 3 * HID + hid, DIN, 1);
    f16x8 Wh00 = LD8(Whh, 0 * HID + hid, HID, 0), Wh01 = LD8(Whh, 0 * HID + hid, HID, 1);
    f16x8 Wh02 = LD8(Whh, 0 * HID + hid, HID, 2), Wh03 = LD8(Whh, 0 * HID + hid, HID, 3);
    f16x8 Wh10 = LD8(Whh, 1 * HID + hid, HID, 0), Wh11 = LD8(Whh, 1 * HID + hid, HID, 1);
    f16x8 Wh12 = LD8(Whh, 1 * HID + hid, HID, 2), Wh13 = LD8(Whh, 1 * HID + hid, HID, 3);
    f16x8 Wh20 = LD8(Whh, 2 * HID + hid, HID, 0), Wh21 = LD8(Whh, 2 * HID + hid, HID, 1);
    f16x8 Wh22 = LD8(Whh, 2 * HID + hid, HID, 2), Wh23 = LD8(Whh, 2 * HID + hid, HID, 3);
    f16x8 Wh30 = LD8(Whh, 3 * HID + hid, HID, 0), Wh31 = LD8(Whh, 3 * HID + hid, HID, 1);
    f16x8 Wh32 = LD8(Whh, 3 * HID + hid, HID, 2), Wh33 = LD8(Whh, 3 * HID + hid, HID, 3);
    asm("" : "+a"(Wx00), "+a"(Wx01), "+a"(Wx10), "+a"(Wx11),
             "+a"(Wx20), "+a"(Wx21), "+a"(Wx30), "+a"(Wx31));
    asm("" : "+a"(Wh00), "+a"(Wh01), "+a"(Wh02), "+a"(Wh03),
             "+a"(Wh10), "+a"(Wh11), "+a"(Wh12), "+a"(Wh13));
    asm("" : "+a"(Wh20), "+a"(Wh21), "+a"(Wh22), "+a"(Wh23),
             "+a"(Wh30), "+a"(Wh31), "+a"(Wh32), "+a"(Wh33));

    const float bs0 = bih[0 * HID + hid] + bhh[0 * HID + hid];
    const float bs1 = bih[1 * HID + hid] + bhh[1 * HID + hid];
    const float bs2 = bih[2 * HID + hid] + bhh[2 * HID + hid];
    const float bs3 = bih[3 * HID + hid] + bhh[3 * HID + hid];

    float cc = cstate[(size_t)b * HID + hid];
    float hv = hstate[(size_t)b * HID + hid];
    if (kg == 0) h_lds[0][hid] = (_Float16)hv;

    // GEMM A-load base: lane reads x[b][t0+sc+col][kg*8 + j] (row = timestep = col)
    const float* xA = x + (size_t)b * TLEN * DIN + (size_t)col * DIN + kg * 8;
    _Float16* y0p = y0 + (size_t)b * HID + hid;

    const int nt = t1 - t0;                       // multiple of SC by construction
    for (int sc = 0; sc < nt; sc += SC) {
        // ---- GEMM phase: xacc[tl][hid][n] = bias_n + x[t0+sc+tl]·Wx_n ----
        {
            const float* pa = xA + (size_t)(t0 + sc) * DIN;
            f16x8 A0 = pack8(*(const float4*)pa,        *(const float4*)(pa + 4));
            f16x8 A1 = pack8(*(const float4*)(pa + 32), *(const float4*)(pa + 36));
            f32x4 g0 = splat4(bs0), g1 = splat4(bs1), g2 = splat4(bs2), g3 = splat4(bs3);
            g0 = MFMA16(A0, Wx00, g0); g1 = MFMA16(A0, Wx10, g1);
            g2 = MFMA16(A0, Wx20, g2); g3 = MFMA16(A0, Wx30, g3);
            g0 = MFMA16(A1, Wx01, g0); g1 = MFMA16(A1, Wx11, g1);
            g2 = MFMA16(A1, Wx21, g2); g3 = MFMA16(A1, Wx31, g3);
            #pragma unroll
            for (int r = 0; r < 4; ++r) {
                const int tl = kg * 4 + r;        // C row = (lane>>4)*4 + reg
                float* d = &xacc[(tl * HID + hid) * 4];
                d[0] = g0[r]; d[1] = g1[r]; d[2] = g2[r]; d[3] = g3[r];
            }
        }
        BARRIER();
        // ---- 16 steady steps: h-recurrence only ----
        for (int s = 0; s < SC; s += 2) {
            {
                H_STEP_CORE(s, 0)
                if (kg == 0) {
                    h_lds[1][hid] = (_Float16)hv;
                    y0p[(size_t)(sc + s) * (BATCH * HID)] = (_Float16)hv;
                }
                BARRIER();
            }
            {
                H_STEP_CORE(s + 1, 1)
                if (kg == 0) {
                    h_lds[0][hid] = (_Float16)hv;
                    y0p[(size_t)(sc + s + 1) * (BATCH * HID)] = (_Float16)hv;
                }
                BARRIER();
            }
        }
    }
    if (kg == 0) {
        cstate[(size_t)b * HID + hid] = cc;
        hstate[(size_t)b * HID + hid] = hv;
    }
}

// ===================== Layer 1 =====================
// Same structure; A of the GEMM phase comes from the f16 y0 slab; Wy is
// reloaded from global each sub-chunk (L2-resident) to stay in register budget.
__global__ void __attribute__((amdgpu_flat_work_group_size(512, 512), amdgpu_waves_per_eu(2, 2)))
lstm_l1(const _Float16* __restrict__ y0in,
        const float* __restrict__ Wih, const float* __restrict__ Whh,
        const float* __restrict__ bih, const float* __restrict__ bhh,
        float* __restrict__ hstate, float* __restrict__ cstate,
        int t0, int t1)
{
    const int b    = blockIdx.x;
    const int tid  = threadIdx.x;
    const int lane = tid & 63;
    const int wave = tid >> 6;
    const int col  = lane & 15, kg = lane >> 4;
    const int hid  = wave * 16 + col;

    __shared__ __align__(16) float    xacc[SC * HID * 4];   // 32 KB (yacc)
    __shared__ __align__(16) _Float16 h_lds[2][HID];

    // ---- recurrent weights (AGPR-pinned, held) ----
    f16x8 Wh00 = LD8(Whh, 0 * HID + hid, HID, 0), Wh01 = LD8(Whh, 0 * HID + hid, HID, 1);
    f16x8 Wh02 = LD8(Whh, 0 * HID + hid, HID, 2), Wh03 = LD8(Whh, 0 * HID + hid, HID, 3);
    f16x8 Wh10 = LD8(Whh, 1 * HID + hid, HID, 0), Wh11 = LD8(Whh, 1 * HID + hid, HID, 1);
    f16x8 Wh12 = LD8(Whh, 1 * HID + hid, HID, 2), Wh13 = LD8(Whh, 1 * HID + hid, HID, 3);
    f16x8 Wh20 = LD8(Whh, 2 * HID + hid, HID, 0), Wh21 = LD8(Whh, 2 * HID + hid, HID, 1);
    f16x8 Wh22 = LD8(Whh, 2 * HID + hid, HID, 2), Wh23 = LD8(Whh, 2 * HID + hid, HID, 3);
    f16x8 Wh30 = LD8(Whh, 3 * HID + hid, HID, 0), Wh31 = LD8(Whh, 3 * HID + hid, HID, 1);
    f16x8 Wh32 = LD8(Whh, 3 * HID + hid, HID, 2), Wh33 = LD8(Whh, 3 * HID + hid, HID, 3);
    asm("" : "+a"(Wh00), "+a"(Wh01), "+a"(Wh02), "+a"(Wh03),
             "+a"(Wh10), "+a"(Wh11), "+a"(Wh12), "+a"(Wh13));
    asm("" : "+a"(Wh20), "+a"(Wh21), "+a"(Wh22), "+a"(Wh23),
             "+a"(Wh30), "+a"(Wh31), "+a"(Wh32), "+a"(Wh33));

    const float bs0 = bih[0 * HID + hid] + bhh[0 * HID + hid];
    const float bs1 = bih[1 * HID + hid] + bhh[1 * HID + hid];
    const float bs2 = bih[2 * HID + hid] + bhh[2 * HID + hid];
    const float bs3 = bih[3 * HID + hid] + bhh[3 * HID + hid];

    float cc = cstate[(size_t)b * HID + hid];
    float hv = hstate[(size_t)b * HID + hid];
    if (kg == 0) h_lds[0][hid] = (_Float16)hv;

    // GEMM A-load base: lane reads y0[rel=sc+col][b][kg*8 + j]
    const _Float16* yA = y0in + ((size_t)col * BATCH + b) * HID + kg * 8;

    const int nt = t1 - t0;
    for (int sc = 0; sc < nt; sc += SC) {
        // ---- GEMM phase: yacc = bias + y0·Wy (Wy reloaded, transient regs) ----
        {
            f16x8 Wy00 = LD8(Wih, 0 * HID + hid, HID, 0), Wy01 = LD8(Wih, 0 * HID + hid, HID, 1);
            f16x8 Wy02 = LD8(Wih, 0 * HID + hid, HID, 2), Wy03 = LD8(Wih, 0 * HID + hid, HID, 3);
            f16x8 Wy10 = LD8(Wih, 1 * HID + hid, HID, 0), Wy11 = LD8(Wih, 1 * HID + hid, HID, 1);
            f16x8 Wy12 = LD8(Wih, 1 * HID + hid, HID, 2), Wy13 = LD8(Wih, 1 * HID + hid, HID, 3);
            f16x8 Wy20 = LD8(Wih, 2 * HID + hid, HID, 0), Wy21 = LD8(Wih, 2 * HID + hid, HID, 1);
            f16x8 Wy22 = LD8(Wih, 2 * HID + hid, HID, 2), Wy23 = LD8(Wih, 2 * HID + hid, HID, 3);
            f16x8 Wy30 = LD8(Wih, 3 * HID + hid, HID, 0), Wy31 = LD8(Wih, 3 * HID + hid, HID, 1);
            f16x8 Wy32 = LD8(Wih, 3 * HID + hid, HID, 2), Wy33 = LD8(Wih, 3 * HID + hid, HID, 3);
            const _Float16* pa = yA + (size_t)sc * (BATCH * HID);
            f16x8 A0 = *(const f16x8*)(pa);
            f16x8 A1 = *(const f16x8*)(pa + 32);
            f16x8 A2 = *(const f16x8*)(pa + 64);
            f16x8 A3 = *(const f16x8*)(pa + 96);
            f32x4 g0 = splat4(bs0), g1 = splat4(bs1), g2 = splat4(bs2), g3 = splat4(bs3);
            g0 = MFMA16(A0, Wy00, g0); g1 = MFMA16(A0, Wy10, g1);
            g2 = MFMA16(A0, Wy20, g2); g3 = MFMA16(A0, Wy30, g3);
            g0 = MFMA16(A1, Wy01, g0); g1 = MFMA16(A1, Wy11, g1);
            g2 = MFMA16(A1, Wy21, g2); g3 = MFMA16(A1, Wy31, g3);
            g0 = MFMA16(A2, Wy02, g0); g1 = MFMA16(A2, Wy12, g1);
            g2 = MFMA16(A2, Wy22, g2); g3 = MFMA16(A2, Wy32, g3);
            g0 = MFMA16(A3, Wy03, g0); g1 = MFMA16(A3, Wy13, g1);
            g2 = MFMA16(A3, Wy23, g2); g3 = MFMA16(A3, Wy33, g3);
            #pragma unroll
            for (int r = 0; r < 4; ++r) {
                const int tl = kg * 4 + r;
                float* d = &xacc[(tl * HID + hid) * 4];
                d[0] = g0[r]; d[1] = g1[r]; d[2] = g2[r]; d[3] = g3[r];
            }
        }
        BARRIER();
        // ---- 16 steady steps ----
        for (int s = 0; s < SC; s += 2) {
            {
                H_STEP_CORE(s, 0)
                if (kg == 0) h_lds[1][hid] = (_Float16)hv;
                BARRIER();
            }
            {
                H_STEP_CORE(s + 1, 1)
                if (kg == 0) h_lds[0][hid] = (_Float16)hv;
                BARRIER();
            }
        }
    }
    if (kg == 0) {
        cstate[(size_t)b * HID + hid] = cc;
        hstate[(size_t)b * HID + hid] = hv;   // final h1 (fc reads this)
    }
}

// ===================== Final FC =====================
__global__ __launch_bounds__(128) void fc_kernel(
    const float* __restrict__ h1, const float* __restrict__ Wfc,
    const float* __restrict__ bfc, float* __restrict__ out)
{
    const int b = blockIdx.x;
    const int o = threadIdx.x;
    __shared__ float hs[HID];
    hs[o] = h1[(size_t)b * HID + o];
    __syncthreads();
    if (o < NOUT) {
        const float4* w  = reinterpret_cast<const float4*>(Wfc + (size_t)o * HID);
        const float4* hv = reinterpret_cast<const float4*>(hs);
        float acc = bfc[o];
        #pragma unroll
        for (int q = 0; q < HID / 4; ++q) {
            float4 wv = w[q]; float4 h4 = hv[q];
            acc = fmaf(wv.x, h4.x, fmaf(wv.y, h4.y, fmaf(wv.z, h4.z, fmaf(wv.w, h4.w, acc))));
        }
        out[(size_t)b * NOUT + o] = acc;
    }
}

extern "C" void kernel_launch(void* const* d_in, const int* in_sizes, int n_in,
                              void* d_out, int out_size, void* d_ws, size_t ws_size,
                              hipStream_t stream) {
    const float* x    = (const float*)d_in[0];
    const float* Wih0 = (const float*)d_in[1];
    const float* Whh0 = (const float*)d_in[2];
    const float* bih0 = (const float*)d_in[3];
    const float* bhh0 = (const float*)d_in[4];
    const float* Wih1 = (const float*)d_in[5];
    const float* Whh1 = (const float*)d_in[6];
    const float* bih1 = (const float*)d_in[7];
    const float* bhh1 = (const float*)d_in[8];
    const float* Wfc  = (const float*)d_in[9];
    const float* bfc  = (const float*)d_in[10];
    float* out = (float*)d_out;

    // ws: hst0 | cst0 | hst1 | cst1 (f32, 128KB each) then y0 slab (f16)
    float* hst0 = (float*)d_ws;
    float* cst0 = hst0 + BATCH * HID;
    float* hst1 = cst0 + BATCH * HID;
    float* cst1 = hst1 + BATCH * HID;
    _Float16* y0 = (_Float16*)(cst1 + BATCH * HID);

    const size_t stateBytes = (size_t)4 * BATCH * HID * sizeof(float);   // 512 KB
    size_t avail = ws_size > stateBytes ? ws_size - stateBytes : 0;
    int Tc = (int)(avail / ((size_t)BATCH * HID * 2));
    if (Tc > TLEN) Tc = TLEN;
    Tc &= ~(SC - 1);                  // sub-chunk multiple
    if (Tc < SC) Tc = SC;

    hipMemsetAsync(d_ws, 0, stateBytes, stream);

    for (int t0 = 0; t0 < TLEN; t0 += Tc) {
        int t1 = t0 + Tc; if (t1 > TLEN) t1 = TLEN;
        lstm_l0<<<BATCH, 512, 0, stream>>>(x, Wih0, Whh0, bih0, bhh0, hst0, cst0, y0, t0, t1);
        lstm_l1<<<BATCH, 512, 0, stream>>>(y0, Wih1, Whh1, bih1, bhh1, hst1, cst1, t0, t1);
    }
    fc_kernel<<<BATCH, 128, 0, stream>>>(hst1, Wfc, bfc, out);
}

// Round 16
// 583.058 us; speedup vs baseline: 1.6845x; 1.0487x over previous
//
#include <hip/hip_runtime.h>

#define BATCH 256
#define TLEN  512
#define DIN   64
#define HID   128
#define NOUT  40
#define SC    16   // sub-chunk: input projections precomputed 16 steps at a time

typedef _Float16 f16x8 __attribute__((ext_vector_type(8)));
typedef float    f32x4 __attribute__((ext_vector_type(4)));

#define MFMA16(a, b, c) __builtin_amdgcn_mfma_f32_16x16x32_f16((a), (b), (c), 0, 0, 0)

// LDS-visibility barrier only: no vmcnt drain.
#define BARRIER() do {                                      \
    asm volatile("s_waitcnt lgkmcnt(0)" ::: "memory");      \
    __builtin_amdgcn_s_barrier();                           \
} while (0)

static __device__ __forceinline__ f16x8 pack8(float4 a, float4 b) {
    f16x8 v;
    v[0] = (_Float16)a.x; v[1] = (_Float16)a.y; v[2] = (_Float16)a.z; v[3] = (_Float16)a.w;
    v[4] = (_Float16)b.x; v[5] = (_Float16)b.y; v[6] = (_Float16)b.z; v[7] = (_Float16)b.w;
    return v;
}
static __device__ __forceinline__ float sig_(float x) {
    return __builtin_amdgcn_rcpf(1.0f + __expf(-x));
}
static __device__ __forceinline__ float tanh_(float x) {
    return fmaf(-2.0f, __builtin_amdgcn_rcpf(__expf(2.0f * x) + 1.0f), 1.0f);
}
static __device__ __forceinline__ f32x4 splat4(float v) { return (f32x4){v, v, v, v}; }

// Weight fragment loader; uses kernel-local `kg`. k = kt*32 + kg*8 + j.
#define LD8(base, g, K, kt) pack8(*(const float4*)((base) + (size_t)(g) * (K) + (kt) * 32 + kg * 8), \
                                  *(const float4*)((base) + (size_t)(g) * (K) + (kt) * 32 + kg * 8 + 4))

// One K-round of the h-recurrence: 8 chains (4 gates x 2 hid-halves).
#define HROUND(H, KT)                                                           \
    aA0 = MFMA16(H, WhA0_##KT, aA0); aA1 = MFMA16(H, WhA1_##KT, aA1);           \
    aA2 = MFMA16(H, WhA2_##KT, aA2); aA3 = MFMA16(H, WhA3_##KT, aA3);           \
    aB0 = MFMA16(H, WhB0_##KT, aB0); aB1 = MFMA16(H, WhB1_##KT, aB1);           \
    aB2 = MFMA16(H, WhB2_##KT, aB2); aB3 = MFMA16(H, WhB3_##KT, aB3);

// Steady step core: 4 h-frag reads, xi prefetch for next step, 32 MFMA, 2-cell ACT.
// Uses kernel-locals: xacc, h_lds, hidA, hidB, kg, ccA, ccB, hvA, hvB, z4, Wh*.
#define H_STEP_CORE(S, P, XIA, XIB, XIAN, XIBN)                                 \
    const _Float16* hb = &h_lds[P][0];                                          \
    f16x8 h0 = *(const f16x8*)(hb + kg * 8);                                    \
    f16x8 h1 = *(const f16x8*)(hb + 32 + kg * 8);                               \
    f16x8 h2 = *(const f16x8*)(hb + 64 + kg * 8);                               \
    f16x8 h3 = *(const f16x8*)(hb + 96 + kg * 8);                               \
    { int sn = (S) + 1 < SC ? (S) + 1 : SC - 1;                                 \
      XIAN = *(const f32x4*)&xacc[(sn * HID + hidA) * 4];                       \
      XIBN = *(const f32x4*)&xacc[(sn * HID + hidB) * 4]; }                     \
    f32x4 aA0 = z4, aA1 = z4, aA2 = z4, aA3 = z4;                               \
    f32x4 aB0 = z4, aB1 = z4, aB2 = z4, aB3 = z4;                               \
    HROUND(h0, 0)                                                               \
    HROUND(h1, 1)                                                               \
    HROUND(h2, 2)                                                               \
    HROUND(h3, 3)                                                               \
    float ivA = sig_(aA0[0] + XIA[0]), fvA = sig_(aA1[0] + XIA[1]);             \
    float gvA = tanh_(aA2[0] + XIA[2]), ovA = sig_(aA3[0] + XIA[3]);            \
    ccA = fmaf(fvA, ccA, ivA * gvA);                                            \
    hvA = ovA * tanh_(ccA);                                                     \
    float ivB = sig_(aB0[0] + XIB[0]), fvB = sig_(aB1[0] + XIB[1]);             \
    float gvB = tanh_(aB2[0] + XIB[2]), ovB = sig_(aB3[0] + XIB[3]);            \
    ccB = fmaf(fvB, ccB, ivB * gvB);                                            \
    hvB = ovB * tanh_(ccB);

// ===================== Layer 0 =====================
// 256 blocks (one batch) x 256 thr (4 waves; 1 wave/SIMD). Wave w owns hid
// [w*32, w*32+32) = tiles A,B x 4 gates. Per SC steps: GEMM phase fills
// xacc[t][hid][4] = bias + x_t·Wx; steady step = 32 h-MFMAs + 2-cell ACT.
__global__ void __attribute__((amdgpu_flat_work_group_size(256, 256), amdgpu_waves_per_eu(1, 1)))
lstm_l0(const float* __restrict__ x,
        const float* __restrict__ Wih, const float* __restrict__ Whh,
        const float* __restrict__ bih, const float* __restrict__ bhh,
        float* __restrict__ hstate, float* __restrict__ cstate,
        _Float16* __restrict__ y0, int t0, int t1)
{
    const int b    = blockIdx.x;
    const int tid  = threadIdx.x;
    const int lane = tid & 63;
    const int wave = tid >> 6;           // 0..3
    const int col  = lane & 15, kg = lane >> 4;
    const int hidA = wave * 32 + col;
    const int hidB = hidA + 16;

    __shared__ __align__(16) float    xacc[SC * HID * 4];   // 32 KB
    __shared__ __align__(16) _Float16 h_lds[2][HID];

    // ---- weight fragments (AGPR-pinned): Wx 16 + Wh 32 frags = 192 AGPR ----
    f16x8 WxA0_0 = LD8(Wih, 0 * HID + hidA, DIN, 0), WxA0_1 = LD8(Wih, 0 * HID + hidA, DIN, 1);
    f16x8 WxA1_0 = LD8(Wih, 1 * HID + hidA, DIN, 0), WxA1_1 = LD8(Wih, 1 * HID + hidA, DIN, 1);
    f16x8 WxA2_0 = LD8(Wih, 2 * HID + hidA, DIN, 0), WxA2_1 = LD8(Wih, 2 * HID + hidA, DIN, 1);
    f16x8 WxA3_0 = LD8(Wih, 3 * HID + hidA, DIN, 0), WxA3_1 = LD8(Wih, 3 * HID + hidA, DIN, 1);
    f16x8 WxB0_0 = LD8(Wih, 0 * HID + hidB, DIN, 0), WxB0_1 = LD8(Wih, 0 * HID + hidB, DIN, 1);
    f16x8 WxB1_0 = LD8(Wih, 1 * HID + hidB, DIN, 0), WxB1_1 = LD8(Wih, 1 * HID + hidB, DIN, 1);
    f16x8 WxB2_0 = LD8(Wih, 2 * HID + hidB, DIN, 0), WxB2_1 = LD8(Wih, 2 * HID + hidB, DIN, 1);
    f16x8 WxB3_0 = LD8(Wih, 3 * HID + hidB, DIN, 0), WxB3_1 = LD8(Wih, 3 * HID + hidB, DIN, 1);
    f16x8 WhA0_0 = LD8(Whh, 0 * HID + hidA, HID, 0), WhA0_1 = LD8(Whh, 0 * HID + hidA, HID, 1);
    f16x8 WhA0_2 = LD8(Whh, 0 * HID + hidA, HID, 2), WhA0_3 = LD8(Whh, 0 * HID + hidA, HID, 3);
    f16x8 WhA1_0 = LD8(Whh, 1 * HID + hidA, HID, 0), WhA1_1 = LD8(Whh, 1 * HID + hidA, HID, 1);
    f16x8 WhA1_2 = LD8(Whh, 1 * HID + hidA, HID, 2), WhA1_3 = LD8(Whh, 1 * HID + hidA, HID, 3);
    f16x8 WhA2_0 = LD8(Whh, 2 * HID + hidA, HID, 0), WhA2_1 = LD8(Whh, 2 * HID + hidA, HID, 1);
    f16x8 WhA2_2 = LD8(Whh, 2 * HID + hidA, HID, 2), WhA2_3 = LD8(Whh, 2 * HID + hidA, HID, 3);
    f16x8 WhA3_0 = LD8(Whh, 3 * HID + hidA, HID, 0), WhA3_1 = LD8(Whh, 3 * HID + hidA, HID, 1);
    f16x8 WhA3_2 = LD8(Whh, 3 * HID + hidA, HID, 2), WhA3_3 = LD8(Whh, 3 * HID + hidA, HID, 3);
    f16x8 WhB0_0 = LD8(Whh, 0 * HID + hidB, HID, 0), WhB0_1 = LD8(Whh, 0 * HID + hidB, HID, 1);
    f16x8 WhB0_2 = LD8(Whh, 0 * HID + hidB, HID, 2), WhB0_3 = LD8(Whh, 0 * HID + hidB, HID, 3);
    f16x8 WhB1_0 = LD8(Whh, 1 * HID + hidB, HID, 0), WhB1_1 = LD8(Whh, 1 * HID + hidB, HID, 1);
    f16x8 WhB1_2 = LD8(Whh, 1 * HID + hidB, HID, 2), WhB1_3 = LD8(Whh, 1 * HID + hidB, HID, 3);
    f16x8 WhB2_0 = LD8(Whh, 2 * HID + hidB, HID, 0), WhB2_1 = LD8(Whh, 2 * HID + hidB, HID, 1);
    f16x8 WhB2_2 = LD8(Whh, 2 * HID + hidB, HID, 2), WhB2_3 = LD8(Whh, 2 * HID + hidB, HID, 3);
    f16x8 WhB3_0 = LD8(Whh, 3 * HID + hidB, HID, 0), WhB3_1 = LD8(Whh, 3 * HID + hidB, HID, 1);
    f16x8 WhB3_2 = LD8(Whh, 3 * HID + hidB, HID, 2), WhB3_3 = LD8(Whh, 3 * HID + hidB, HID, 3);
    asm("" : "+a"(WxA0_0), "+a"(WxA0_1), "+a"(WxA1_0), "+a"(WxA1_1),
             "+a"(WxA2_0), "+a"(WxA2_1), "+a"(WxA3_0), "+a"(WxA3_1));
    asm("" : "+a"(WxB0_0), "+a"(WxB0_1), "+a"(WxB1_0), "+a"(WxB1_1),
             "+a"(WxB2_0), "+a"(WxB2_1), "+a"(WxB3_0), "+a"(WxB3_1));
    asm("" : "+a"(WhA0_0), "+a"(WhA0_1), "+a"(WhA0_2), "+a"(WhA0_3),
             "+a"(WhA1_0), "+a"(WhA1_1), "+a"(WhA1_2), "+a"(WhA1_3));
    asm("" : "+a"(WhA2_0), "+a"(WhA2_1), "+a"(WhA2_2), "+a"(WhA2_3),
             "+a"(WhA3_0), "+a"(WhA3_1), "+a"(WhA3_2), "+a"(WhA3_3));
    asm("" : "+a"(WhB0_0), "+a"(WhB0_1), "+a"(WhB0_2), "+a"(WhB0_3),
             "+a"(WhB1_0), "+a"(WhB1_1), "+a"(WhB1_2), "+a"(WhB1_3));
    asm("" : "+a"(WhB2_0), "+a"(WhB2_1), "+a"(WhB2_2), "+a"(WhB2_3),
             "+a"(WhB3_0), "+a"(WhB3_1), "+a"(WhB3_2), "+a"(WhB3_3));

    const float bsA0 = bih[0 * HID + hidA] + bhh[0 * HID + hidA];
    const float bsA1 = bih[1 * HID + hidA] + bhh[1 * HID + hidA];
    const float bsA2 = bih[2 * HID + hidA] + bhh[2 * HID + hidA];
    const float bsA3 = bih[3 * HID + hidA] + bhh[3 * HID + hidA];
    const float bsB0 = bih[0 * HID + hidB] + bhh[0 * HID + hidB];
    const float bsB1 = bih[1 * HID + hidB] + bhh[1 * HID + hidB];
    const float bsB2 = bih[2 * HID + hidB] + bhh[2 * HID + hidB];
    const float bsB3 = bih[3 * HID + hidB] + bhh[3 * HID + hidB];
    const f32x4 z4 = {0.f, 0.f, 0.f, 0.f};

    float ccA = cstate[(size_t)b * HID + hidA];
    float ccB = cstate[(size_t)b * HID + hidB];
    float hvA = hstate[(size_t)b * HID + hidA];
    float hvB = hstate[(size_t)b * HID + hidB];
    if (kg == 0) { h_lds[0][hidA] = (_Float16)hvA; h_lds[0][hidB] = (_Float16)hvB; }

    // GEMM A-base: lane reads x[b][t+col][kg*8 + j] (A row = timestep = col)
    const float* xA = x + (size_t)b * TLEN * DIN + (size_t)col * DIN + kg * 8;
    _Float16* y0pA = y0 + (size_t)b * HID + hidA;
    _Float16* y0pB = y0 + (size_t)b * HID + hidB;

    f32x4 xiA0, xiB0, xiA1, xiB1;

    const int nt = t1 - t0;                       // multiple of SC
    for (int sc = 0; sc < nt; sc += SC) {
        // ---- GEMM phase: xacc[tl][hid][n] = bias_n + x_t·Wx_n ----
        {
            const float* pa = xA + (size_t)(t0 + sc) * DIN;
            f16x8 A0 = pack8(*(const float4*)pa,        *(const float4*)(pa + 4));
            f16x8 A1 = pack8(*(const float4*)(pa + 32), *(const float4*)(pa + 36));
            f32x4 gA0 = splat4(bsA0), gA1 = splat4(bsA1), gA2 = splat4(bsA2), gA3 = splat4(bsA3);
            f32x4 gB0 = splat4(bsB0), gB1 = splat4(bsB1), gB2 = splat4(bsB2), gB3 = splat4(bsB3);
            gA0 = MFMA16(A0, WxA0_0, gA0); gA1 = MFMA16(A0, WxA1_0, gA1);
            gA2 = MFMA16(A0, WxA2_0, gA2); gA3 = MFMA16(A0, WxA3_0, gA3);
            gB0 = MFMA16(A0, WxB0_0, gB0); gB1 = MFMA16(A0, WxB1_0, gB1);
            gB2 = MFMA16(A0, WxB2_0, gB2); gB3 = MFMA16(A0, WxB3_0, gB3);
            gA0 = MFMA16(A1, WxA0_1, gA0); gA1 = MFMA16(A1, WxA1_1, gA1);
            gA2 = MFMA16(A1, WxA2_1, gA2); gA3 = MFMA16(A1, WxA3_1, gA3);
            gB0 = MFMA16(A1, WxB0_1, gB0); gB1 = MFMA16(A1, WxB1_1, gB1);
            gB2 = MFMA16(A1, WxB2_1, gB2); gB3 = MFMA16(A1, WxB3_1, gB3);
            #pragma unroll
            for (int r = 0; r < 4; ++r) {
                const int tl = kg * 4 + r;        // C row = (lane>>4)*4 + reg
                *(float4*)&xacc[(tl * HID + hidA) * 4] = make_float4(gA0[r], gA1[r], gA2[r], gA3[r]);
                *(float4*)&xacc[(tl * HID + hidB) * 4] = make_float4(gB0[r], gB1[r], gB2[r], gB3[r]);
            }
        }
        BARRIER();
        xiA0 = *(const f32x4*)&xacc[(0 * HID + hidA) * 4];
        xiB0 = *(const f32x4*)&xacc[(0 * HID + hidB) * 4];
        // ---- 16 steady steps ----
        for (int s = 0; s < SC; s += 2) {
            {
                H_STEP_CORE(s, 0, xiA0, xiB0, xiA1, xiB1)
                if (kg == 0) {
                    _Float16 hA = (_Float16)hvA, hB = (_Float16)hvB;
                    h_lds[1][hidA] = hA; h_lds[1][hidB] = hB;
                    y0pA[(size_t)(sc + s) * (BATCH * HID)] = hA;
                    y0pB[(size_t)(sc + s) * (BATCH * HID)] = hB;
                }
                BARRIER();
            }
            {
                H_STEP_CORE(s + 1, 1, xiA1, xiB1, xiA0, xiB0)
                if (kg == 0) {
                    _Float16 hA = (_Float16)hvA, hB = (_Float16)hvB;
                    h_lds[0][hidA] = hA; h_lds[0][hidB] = hB;
                    y0pA[(size_t)(sc + s + 1) * (BATCH * HID)] = hA;
                    y0pB[(size_t)(sc + s + 1) * (BATCH * HID)] = hB;
                }
                BARRIER();
            }
        }
    }
    if (kg == 0) {
        cstate[(size_t)b * HID + hidA] = ccA;
        cstate[(size_t)b * HID + hidB] = ccB;
        hstate[(size_t)b * HID + hidA] = hvA;
        hstate[(size_t)b * HID + hidB] = hvB;
    }
}

// ===================== Layer 1 =====================
// Same structure; GEMM A comes from the f16 y0 slab; Wy loaded per chunk
// (512-reg budget at 1 wave/EU -> no spill; Wh held in 128 AGPR).
__global__ void __attribute__((amdgpu_flat_work_group_size(256, 256), amdgpu_waves_per_eu(1, 1)))
lstm_l1(const _Float16* __restrict__ y0in,
        const float* __restrict__ Wih, const float* __restrict__ Whh,
        const float* __restrict__ bih, const float* __restrict__ bhh,
        float* __restrict__ hstate, float* __restrict__ cstate,
        int t0, int t1)
{
    const int b    = blockIdx.x;
    const int tid  = threadIdx.x;
    const int lane = tid & 63;
    const int wave = tid >> 6;
    const int col  = lane & 15, kg = lane >> 4;
    const int hidA = wave * 32 + col;
    const int hidB = hidA + 16;

    __shared__ __align__(16) float    xacc[SC * HID * 4];   // 32 KB (yacc)
    __shared__ __align__(16) _Float16 h_lds[2][HID];

    // ---- recurrent weights (AGPR-pinned, held): 32 frags = 128 AGPR ----
    f16x8 WhA0_0 = LD8(Whh, 0 * HID + hidA, HID, 0), WhA0_1 = LD8(Whh, 0 * HID + hidA, HID, 1);
    f16x8 WhA0_2 = LD8(Whh, 0 * HID + hidA, HID, 2), WhA0_3 = LD8(Whh, 0 * HID + hidA, HID, 3);
    f16x8 WhA1_0 = LD8(Whh, 1 * HID + hidA, HID, 0), WhA1_1 = LD8(Whh, 1 * HID + hidA, HID, 1);
    f16x8 WhA1_2 = LD8(Whh, 1 * HID + hidA, HID, 2), WhA1_3 = LD8(Whh, 1 * HID + hidA, HID, 3);
    f16x8 WhA2_0 = LD8(Whh, 2 * HID + hidA, HID, 0), WhA2_1 = LD8(Whh, 2 * HID + hidA, HID, 1);
    f16x8 WhA2_2 = LD8(Whh, 2 * HID + hidA, HID, 2), WhA2_3 = LD8(Whh, 2 * HID + hidA, HID, 3);
    f16x8 WhA3_0 = LD8(Whh, 3 * HID + hidA, HID, 0), WhA3_1 = LD8(Whh, 3 * HID + hidA, HID, 1);
    f16x8 WhA3_2 = LD8(Whh, 3 * HID + hidA, HID, 2), WhA3_3 = LD8(Whh, 3 * HID + hidA, HID, 3);
    f16x8 WhB0_0 = LD8(Whh, 0 * HID + hidB, HID, 0), WhB0_1 = LD8(Whh, 0 * HID + hidB, HID, 1);
    f16x8 WhB0_2 = LD8(Whh, 0 * HID + hidB, HID, 2), WhB0_3 = LD8(Whh, 0 * HID + hidB, HID, 3);
    f16x8 WhB1_0 = LD8(Whh, 1 * HID + hidB, HID, 0), WhB1_1 = LD8(Whh, 1 * HID + hidB, HID, 1);
    f16x8 WhB1_2 = LD8(Whh, 1 * HID + hidB, HID, 2), WhB1_3 = LD8(Whh, 1 * HID + hidB, HID, 3);
    f16x8 WhB2_0 = LD8(Whh, 2 * HID + hidB, HID, 0), WhB2_1 = LD8(Whh, 2 * HID + hidB, HID, 1);
    f16x8 WhB2_2 = LD8(Whh, 2 * HID + hidB, HID, 2), WhB2_3 = LD8(Whh, 2 * HID + hidB, HID, 3);
    f16x8 WhB3_0 = LD8(Whh, 3 * HID + hidB, HID, 0), WhB3_1 = LD8(Whh, 3 * HID + hidB, HID, 1);
    f16x8 WhB3_2 = LD8(Whh, 3 * HID + hidB, HID, 2), WhB3_3 = LD8(Whh, 3 * HID + hidB, HID, 3);
    asm("" : "+a"(WhA0_0), "+a"(WhA0_1), "+a"(WhA0_2), "+a"(WhA0_3),
             "+a"(WhA1_0), "+a"(WhA1_1), "+a"(WhA1_2), "+a"(WhA1_3));
    asm("" : "+a"(WhA2_0), "+a"(WhA2_1), "+a"(WhA2_2), "+a"(WhA2_3),
             "+a"(WhA3_0), "+a"(WhA3_1), "+a"(WhA3_2), "+a"(WhA3_3));
    asm("" : "+a"(WhB0_0), "+a"(WhB0_1), "+a"(WhB0_2), "+a"(WhB0_3),
             "+a"(WhB1_0), "+a"(WhB1_1), "+a"(WhB1_2), "+a"(WhB1_3));
    asm("" : "+a"(WhB2_0), "+a"(WhB2_1), "+a"(WhB2_2), "+a"(WhB2_3),
             "+a"(WhB3_0), "+a"(WhB3_1), "+a"(WhB3_2), "+a"(WhB3_3));

    const float bsA0 = bih[0 * HID + hidA] + bhh[0 * HID + hidA];
    const float bsA1 = bih[1 * HID + hidA] + bhh[1 * HID + hidA];
    const float bsA2 = bih[2 * HID + hidA] + bhh[2 * HID + hidA];
    const float bsA3 = bih[3 * HID + hidA] + bhh[3 * HID + hidA];
    const float bsB0 = bih[0 * HID + hidB] + bhh[0 * HID + hidB];
    const float bsB1 = bih[1 * HID + hidB] + bhh[1 * HID + hidB];
    const float bsB2 = bih[2 * HID + hidB] + bhh[2 * HID + hidB];
    const float bsB3 = bih[3 * HID + hidB] + bhh[3 * HID + hidB];
    const f32x4 z4 = {0.f, 0.f, 0.f, 0.f};

    float ccA = cstate[(size_t)b * HID + hidA];
    float ccB = cstate[(size_t)b * HID + hidB];
    float hvA = hstate[(size_t)b * HID + hidA];
    float hvB = hstate[(size_t)b * HID + hidB];
    if (kg == 0) { h_lds[0][hidA] = (_Float16)hvA; h_lds[0][hidB] = (_Float16)hvB; }

    // GEMM A-base: lane reads y0[rel=sc+col][b][kg*8 + j]
    const _Float16* yA = y0in + ((size_t)col * BATCH + b) * HID + kg * 8;

    f32x4 xiA0, xiB0, xiA1, xiB1;

    const int nt = t1 - t0;
    for (int sc = 0; sc < nt; sc += SC) {
        // ---- GEMM phase: yacc = bias + y0·Wy (Wy loaded per chunk) ----
        {
            f16x8 WyA0_0 = LD8(Wih, 0 * HID + hidA, HID, 0), WyA0_1 = LD8(Wih, 0 * HID + hidA, HID, 1);
            f16x8 WyA0_2 = LD8(Wih, 0 * HID + hidA, HID, 2), WyA0_3 = LD8(Wih, 0 * HID + hidA, HID, 3);
            f16x8 WyA1_0 = LD8(Wih, 1 * HID + hidA, HID, 0), WyA1_1 = LD8(Wih, 1 * HID + hidA, HID, 1);
            f16x8 WyA1_2 = LD8(Wih, 1 * HID + hidA, HID, 2), WyA1_3 = LD8(Wih, 1 * HID + hidA, HID, 3);
            f16x8 WyA2_0 = LD8(Wih, 2 * HID + hidA, HID, 0), WyA2_1 = LD8(Wih, 2 * HID + hidA, HID, 1);
            f16x8 WyA2_2 = LD8(Wih, 2 * HID + hidA, HID, 2), WyA2_3 = LD8(Wih, 2 * HID + hidA, HID, 3);
            f16x8 WyA3_0 = LD8(Wih, 3 * HID + hidA, HID, 0), WyA3_1 = LD8(Wih, 3 * HID + hidA, HID, 1);
            f16x8 WyA3_2 = LD8(Wih, 3 * HID + hidA, HID, 2), WyA3_3 = LD8(Wih, 3 * HID + hidA, HID, 3);
            f16x8 WyB0_0 = LD8(Wih, 0 * HID + hidB, HID, 0), WyB0_1 = LD8(Wih, 0 * HID + hidB, HID, 1);
            f16x8 WyB0_2 = LD8(Wih, 0 * HID + hidB, HID, 2), WyB0_3 = LD8(Wih, 0 * HID + hidB, HID, 3);
            f16x8 WyB1_0 = LD8(Wih, 1 * HID + hidB, HID, 0), WyB1_1 = LD8(Wih, 1 * HID + hidB, HID, 1);
            f16x8 WyB1_2 = LD8(Wih, 1 * HID + hidB, HID, 2), WyB1_3 = LD8(Wih, 1 * HID + hidB, HID, 3);
            f16x8 WyB2_0 = LD8(Wih, 2 * HID + hidB, HID, 0), WyB2_1 = LD8(Wih, 2 * HID + hidB, HID, 1);
            f16x8 WyB2_2 = LD8(Wih, 2 * HID + hidB, HID, 2), WyB2_3 = LD8(Wih, 2 * HID + hidB, HID, 3);
            f16x8 WyB3_0 = LD8(Wih, 3 * HID + hidB, HID, 0), WyB3_1 = LD8(Wih, 3 * HID + hidB, HID, 1);
            f16x8 WyB3_2 = LD8(Wih, 3 * HID + hidB, HID, 2), WyB3_3 = LD8(Wih, 3 * HID + hidB, HID, 3);
            const _Float16* pa = yA + (size_t)sc * (BATCH * HID);
            f16x8 A0 = *(const f16x8*)(pa);
            f16x8 A1 = *(const f16x8*)(pa + 32);
            f16x8 A2 = *(const f16x8*)(pa + 64);
            f16x8 A3 = *(const f16x8*)(pa + 96);
            f32x4 gA0 = splat4(bsA0), gA1 = splat4(bsA1), gA2 = splat4(bsA2), gA3 = splat4(bsA3);
            f32x4 gB0 = splat4(bsB0), gB1 = splat4(bsB1), gB2 = splat4(bsB2), gB3 = splat4(bsB3);
            gA0 = MFMA16(A0, WyA0_0, gA0); gA1 = MFMA16(A0, WyA1_0, gA1);
            gA2 = MFMA16(A0, WyA2_0, gA2); gA3 = MFMA16(A0, WyA3_0, gA3);
            gB0 = MFMA16(A0, WyB0_0, gB0); gB1 = MFMA16(A0, WyB1_0, gB1);
            gB2 = MFMA16(A0, WyB2_0, gB2); gB3 = MFMA16(A0, WyB3_0, gB3);
            gA0 = MFMA16(A1, WyA0_1, gA0); gA1 = MFMA16(A1, WyA1_1, gA1);
            gA2 = MFMA16(A1, WyA2_1, gA2); gA3 = MFMA16(A1, WyA3_1, gA3);
            gB0 = MFMA16(A1, WyB0_1, gB0); gB1 = MFMA16(A1, WyB1_1, gB1);
            gB2 = MFMA16(A1, WyB2_1, gB2); gB3 = MFMA16(A1, WyB3_1, gB3);
            gA0 = MFMA16(A2, WyA0_2, gA0); gA1 = MFMA16(A2, WyA1_2, gA1);
            gA2 = MFMA16(A2, WyA2_2, gA2); gA3 = MFMA16(A2, WyA3_2, gA3);
            gB0 = MFMA16(A2, WyB0_2, gB0); gB1 = MFMA16(A2, WyB1_2, gB1);
            gB2 = MFMA16(A2, WyB2_2, gB2); gB3 = MFMA16(A2, WyB3_2, gB3);
            gA0 = MFMA16(A3, WyA0_3, gA0); gA1 = MFMA16(A3, WyA1_3, gA1);
            gA2 = MFMA16(A3, WyA2_3, gA2); gA3 = MFMA16(A3, WyA3_3, gA3);
            gB0 = MFMA16(A3, WyB0_3, gB0); gB1 = MFMA16(A3, WyB1_3, gB1);
            gB2 = MFMA16(A3, WyB2_3, gB2); gB3 = MFMA16(A3, WyB3_3, gB3);
            #pragma unroll
            for (int r = 0; r < 4; ++r) {
                const int tl = kg * 4 + r;
                *(float4*)&xacc[(tl * HID + hidA) * 4] = make_float4(gA0[r], gA1[r], gA2[r], gA3[r]);
                *(float4*)&xacc[(tl * HID + hidB) * 4] = make_float4(gB0[r], gB1[r], gB2[r], gB3[r]);
            }
        }
        BARRIER();
        xiA0 = *(const f32x4*)&xacc[(0 * HID + hidA) * 4];
        xiB0 = *(const f32x4*)&xacc[(0 * HID + hidB) * 4];
        // ---- 16 steady steps ----
        for (int s = 0; s < SC; s += 2) {
            {
                H_STEP_CORE(s, 0, xiA0, xiB0, xiA1, xiB1)
                if (kg == 0) {
                    h_lds[1][hidA] = (_Float16)hvA;
                    h_lds[1][hidB] = (_Float16)hvB;
                }
                BARRIER();
            }
            {
                H_STEP_CORE(s + 1, 1, xiA1, xiB1, xiA0, xiB0)
                if (kg == 0) {
                    h_lds[0][hidA] = (_Float16)hvA;
                    h_lds[0][hidB] = (_Float16)hvB;
                }
                BARRIER();
            }
        }
    }
    if (kg == 0) {
        cstate[(size_t)b * HID + hidA] = ccA;
        cstate[(size_t)b * HID + hidB] = ccB;
        hstate[(size_t)b * HID + hidA] = hvA;   // final h1 (fc reads this)
        hstate[(size_t)b * HID + hidB] = hvB;
    }
}

// ===================== Final FC =====================
__global__ __launch_bounds__(128) void fc_kernel(
    const float* __restrict__ h1, const float* __restrict__ Wfc,
    const float* __restrict__ bfc, float* __restrict__ out)
{
    const int b = blockIdx.x;
    const int o = threadIdx.x;
    __shared__ float hs[HID];
    hs[o] = h1[(size_t)b * HID + o];
    __syncthreads();
    if (o < NOUT) {
        const float4* w  = reinterpret_cast<const float4*>(Wfc + (size_t)o * HID);
        const float4* hv = reinterpret_cast<const float4*>(hs);
        float acc = bfc[o];
        #pragma unroll
        for (int q = 0; q < HID / 4; ++q) {
            float4 wv = w[q]; float4 h4 = hv[q];
            acc = fmaf(wv.x, h4.x, fmaf(wv.y, h4.y, fmaf(wv.z, h4.z, fmaf(wv.w, h4.w, acc))));
        }
        out[(size_t)b * NOUT + o] = acc;
    }
}

extern "C" void kernel_launch(void* const* d_in, const int* in_sizes, int n_in,
                              void* d_out, int out_size, void* d_ws, size_t ws_size,
                              hipStream_t stream) {
    const float* x    = (const float*)d_in[0];
    const float* Wih0 = (const float*)d_in[1];
    const float* Whh0 = (const float*)d_in[2];
    const float* bih0 = (const float*)d_in[3];
    const float* bhh0 = (const float*)d_in[4];
    const float* Wih1 = (const float*)d_in[5];
    const float* Whh1 = (const float*)d_in[6];
    const float* bih1 = (const float*)d_in[7];
    const float* bhh1 = (const float*)d_in[8];
    const float* Wfc  = (const float*)d_in[9];
    const float* bfc  = (const float*)d_in[10];
    float* out = (float*)d_out;

    // ws: hst0 | cst0 | hst1 | cst1 (f32, 128KB each) then y0 slab (f16)
    float* hst0 = (float*)d_ws;
    float* cst0 = hst0 + BATCH * HID;
    float* hst1 = cst0 + BATCH * HID;
    float* cst1 = hst1 + BATCH * HID;
    _Float16* y0 = (_Float16*)(cst1 + BATCH * HID);

    const size_t stateBytes = (size_t)4 * BATCH * HID * sizeof(float);   // 512 KB
    size_t avail = ws_size > stateBytes ? ws_size - stateBytes : 0;
    int Tc = (int)(avail / ((size_t)BATCH * HID * 2));
    if (Tc > TLEN) Tc = TLEN;
    Tc &= ~(SC - 1);                  // sub-chunk multiple
    if (Tc < SC) Tc = SC;

    hipMemsetAsync(d_ws, 0, stateBytes, stream);

    for (int t0 = 0; t0 < TLEN; t0 += Tc) {
        int t1 = t0 + Tc; if (t1 > TLEN) t1 = TLEN;
        lstm_l0<<<BATCH, 256, 0, stream>>>(x, Wih0, Whh0, bih0, bhh0, hst0, cst0, y0, t0, t1);
        lstm_l1<<<BATCH, 256, 0, stream>>>(y0, Wih1, Whh1, bih1, bhh1, hst1, cst1, t0, t1);
    }
    fc_kernel<<<BATCH, 128, 0, stream>>>(hst1, Wfc, bfc, out);
}